// Round 2
// baseline (1200.501 us; speedup 1.0000x reference)
//
#include <hip/hip_runtime.h>

// Problem constants (fixed by the reference: B=16, D=256, K=64, H=W=96)
#define NDIM  256          // feature dim D
#define NK    64           // codewords K
#define NPIX  9216         // H*W
#define NB    16           // batch
#define TN    64           // pixels per tile (== wavefront size: lane <-> pixel)
#define NT    3            // tiles per block
#define CHUNKS 48          // NPIX / (TN*NT)
#define GRID  (NB * CHUNKS)   // 768 = exactly 3 blocks/CU on 256 CUs

typedef _Float16 half2_t __attribute__((ext_vector_type(2)));
typedef _Float16 half8_t __attribute__((ext_vector_type(8)));

__device__ __forceinline__ float fdot2(half2_t a, half2_t b, float c) {
  // v_dot2_f32_f16: 2 f16 MACs, fp32 accumulate
  return __builtin_amdgcn_fdot2(a, b, c, false);
}

// ws layout (floats), partials mode:
//   Epart   [GRID][NK*NDIM]   = 12,582,912
//   Apart   [GRID][NK]        = 49,152
//   asum    [NB][NK]          = 1,024
//   c2      [NK]              = 64
//   Ch      [NK][NDIM/2] u32  = 8,192 (half2-packed codewords)
#define WS_EPART_F   (GRID * NK * NDIM)
#define WS_APART_F   (GRID * NK)
#define WS_ASUM_F    (NB * NK)
#define WS_NEED_F    (WS_EPART_F + WS_APART_F + WS_ASUM_F + NK + NK * (NDIM/2))

// ---- c2[k] = sum_d C[k][d]^2, and Ch = half2-packed codewords (once, tiny) ----
__global__ void c2ch_kernel(const float* __restrict__ Cw, float* __restrict__ c2,
                            half2_t* __restrict__ Ch) {
  __shared__ float tmp[256];
  const int t = threadIdx.x;
  const int k = t >> 2, q = t & 3;
  float s = 0.f;
  const float* row = Cw + k * NDIM + q * 64;
  for (int i = 0; i < 64; ++i) { float v = row[i]; s += v * v; }
  tmp[t] = s;
  // pack codewords: 64*128 half2, 32 per thread
  for (int j = 0; j < 32; ++j) {
    const int idx = t * 32 + j;
    const float2 v = *(const float2*)(Cw + 2 * idx);
    half2_t h; h.x = (_Float16)v.x; h.y = (_Float16)v.y;
    Ch[idx] = h;
  }
  __syncthreads();
  if (t < NK) c2[t] = tmp[4*t] + tmp[4*t+1] + tmp[4*t+2] + tmp[4*t+3];
}

// ---- fused: stage -> distances (f16 dot2) -> softmax -> aggregation ----
// block = 256 threads = 4 waves; grid = 768.
// Stage:   X fetched ONCE per tile (cooperative), f16 [d][n] in LDS.
// GEMM1:   lane=pixel, wave=k-slab of 16; codewords via uniform s_loads.
// GEMM2:   thread=(k, d-interleave), 64 fp32 accs across NT tiles, f16 dot2.
// Epilogue: non-atomic per-block partial write (mode=1) or atomics (mode=0).
__global__ __launch_bounds__(256, 3) void encode_main(
    const float* __restrict__ X, const half2_t* __restrict__ Ch,
    const float* __restrict__ scale, const float* __restrict__ c2,
    float* __restrict__ Eout, float* __restrict__ Aout, int mode)
{
  // Xtd rows 144 B (16B-aligned, stride 36 dwords): phase-3 b128 reads hit
  // disjoint bank quads; phase-1 u16 reads are 2-lane/dword broadcasts (free)
  __shared__ _Float16 Xtd[NDIM][72];   // f16 X tile, [d][pixel]  (36.9 KB)
  __shared__ _Float16 Al[NK][72];      // softmax weights [k][pix] ( 9.2 KB)
  __shared__ float    red[4][TN];      // cross-wave softmax scratch (1 KB)

  const int tid  = threadIdx.x;
  const int w    = __builtin_amdgcn_readfirstlane(tid >> 6); // wave id 0..3
  const int lane = tid & 63;                                  // pixel in tile
  const int b      = blockIdx.x / CHUNKS;
  const int chunk  = blockIdx.x % CHUNKS;
  const int n_base = chunk * (TN * NT);
  const float* Xb  = X + (size_t)b * NDIM * NPIX;
  const int kbase  = w * 16;     // this wave's k-slab (wave-uniform)
  const int ka     = tid >> 2;   // aggregation: codeword 0..63
  const int dsl    = tid & 3;    // aggregation: d interleave 0..3
  const int np     = tid & 31;   // staging: pixel-pair index
  const int dslab  = tid >> 5;   // staging: d-slab of 32

  float eacc[64];                // E partial [ka][d = 32c+4j+dsl]
#pragma unroll
  for (int i = 0; i < 64; ++i) eacc[i] = 0.f;
  float asum_acc = 0.f;          // sum_n A[n][k=tid] (threads 0..63)

  for (int t = 0; t < NT; ++t) {
    __syncthreads();             // prev tile's phase-3 reads done
    const int n0 = n_base + t * TN;

    // ---- stage: X fetched once, f16-packed pixel pairs ----
    {
      const float* Xg = Xb + (size_t)(dslab * 32) * NPIX + n0 + 2 * np;
#pragma unroll 4
      for (int i = 0; i < 32; ++i) {
        const float2 v = *(const float2*)(Xg + (size_t)i * NPIX);
        half2_t h; h.x = (_Float16)v.x; h.y = (_Float16)v.y;
        *(half2_t*)&Xtd[dslab * 32 + i][2 * np] = h;
      }
    }
    __syncthreads();

    // ---- phase 1: xc + x^2 from LDS, f16 dot2, uniform codewords ----
    float acc[16];
#pragma unroll
    for (int i = 0; i < 16; ++i) acc[i] = 0.f;
    float xsq = 0.f;
#pragma unroll 4
    for (int dp = 0; dp < NDIM / 2; ++dp) {
      half2_t h; h.x = Xtd[2*dp][lane]; h.y = Xtd[2*dp+1][lane];
      xsq = fdot2(h, h, xsq);
#pragma unroll
      for (int kk = 0; kk < 16; ++kk)
        acc[kk] = fdot2(h, Ch[(kbase + kk) * (NDIM/2) + dp], acc[kk]);
    }

    // ---- phase 2: softmax over k (64 values live across the 4 waves) ----
    float sl[16];
    float m = -3.0e38f;
#pragma unroll
    for (int kk = 0; kk < 16; ++kk) {
      const float s = scale[kbase+kk] * (xsq - 2.f*acc[kk] + c2[kbase+kk]);
      sl[kk] = s; m = fmaxf(m, s);
    }
    red[w][lane] = m;
    __syncthreads();
    m = fmaxf(fmaxf(red[0][lane], red[1][lane]),
              fmaxf(red[2][lane], red[3][lane]));
    float psum = 0.f;
#pragma unroll
    for (int kk = 0; kk < 16; ++kk) {
      const float p = __expf(sl[kk] - m); sl[kk] = p; psum += p;
    }
    __syncthreads();             // all max-reads done before reuse
    red[w][lane] = psum;
    __syncthreads();
    const float tot  = red[0][lane] + red[1][lane] + red[2][lane] + red[3][lane];
    const float rinv = 1.f / tot;
#pragma unroll
    for (int kk = 0; kk < 16; ++kk)
      Al[kbase+kk][lane] = (_Float16)(sl[kk] * rinv);
    __syncthreads();             // Al visible to aggregation

    // ---- phase 3: E[ka][d] += sum_l A[ka][l] * X[d][l]  (f16 dot2) ----
    for (int lc = 0; lc < 8; ++lc) {
      const int l0 = lc * 8;
      const half8_t av = *(const half8_t*)&Al[ka][l0];
      const half2_t a0 = __builtin_shufflevector(av, av, 0, 1);
      const half2_t a1 = __builtin_shufflevector(av, av, 2, 3);
      const half2_t a2 = __builtin_shufflevector(av, av, 4, 5);
      const half2_t a3 = __builtin_shufflevector(av, av, 6, 7);
#pragma unroll
      for (int c = 0; c < 8; ++c) {
#pragma unroll
        for (int j = 0; j < 8; ++j) {
          const int d = c*32 + j*4 + dsl;
          const half8_t xv = *(const half8_t*)&Xtd[d][l0];
          float e = eacc[c*8+j];
          e = fdot2(__builtin_shufflevector(xv, xv, 0, 1), a0, e);
          e = fdot2(__builtin_shufflevector(xv, xv, 2, 3), a1, e);
          e = fdot2(__builtin_shufflevector(xv, xv, 4, 5), a2, e);
          e = fdot2(__builtin_shufflevector(xv, xv, 6, 7), a3, e);
          eacc[c*8+j] = e;
        }
      }
      if (tid < NK) {            // asum for codeword row `tid`
        const half8_t sv = *(const half8_t*)&Al[tid][l0];
        const half2_t one = {(_Float16)1.f, (_Float16)1.f};
        asum_acc = fdot2(__builtin_shufflevector(sv, sv, 0, 1), one, asum_acc);
        asum_acc = fdot2(__builtin_shufflevector(sv, sv, 2, 3), one, asum_acc);
        asum_acc = fdot2(__builtin_shufflevector(sv, sv, 4, 5), one, asum_acc);
        asum_acc = fdot2(__builtin_shufflevector(sv, sv, 6, 7), one, asum_acc);
      }
    }
  }

  // ---- epilogue ----
  if (mode) {
    // non-atomic per-block partial (L2-merged streaming writes)
    float* Ebk = Eout + (size_t)blockIdx.x * (NK*NDIM) + ka * NDIM;
#pragma unroll
    for (int c = 0; c < 8; ++c)
#pragma unroll
      for (int j = 0; j < 8; ++j)
        Ebk[c*32 + j*4 + dsl] = eacc[c*8+j];
    if (tid < NK) Aout[blockIdx.x * NK + tid] = asum_acc;
  } else {
    float* Ebk = Eout + ((size_t)b * NK + ka) * NDIM;
#pragma unroll
    for (int c = 0; c < 8; ++c)
#pragma unroll
      for (int j = 0; j < 8; ++j)
        atomicAdd(&Ebk[c*32 + j*4 + dsl], eacc[c*8+j]);
    if (tid < NK) atomicAdd(&Aout[b*NK + tid], asum_acc);
  }
}

// ---- asum[b][k] = sum_c Apart[(b*CHUNKS+c)][k] ----
__global__ void asum_reduce_kernel(const float* __restrict__ Apart,
                                   float* __restrict__ asum) {
  const int i = blockIdx.x * 256 + threadIdx.x;   // 0..1023: b = i>>6, k = i&63
  const int bb = i >> 6, k = i & 63;
  float s = 0.f;
  for (int c = 0; c < CHUNKS; ++c) s += Apart[(bb*CHUNKS + c)*NK + k];
  asum[i] = s;
}

// ---- out = sum_c Epart - asum*C  (partials mode) ----
__global__ void finalize_partials(const float* __restrict__ Epart,
                                  const float* __restrict__ asum,
                                  const float* __restrict__ Cw,
                                  float* __restrict__ out) {
  const int i = blockIdx.x * 256 + threadIdx.x;
  const int bb = i >> 14;            // batch
  const int o  = i & 16383;          // k*256+d within batch
  const int k  = o >> 8, d = i & 255;
  float s = 0.f;
#pragma unroll 4
  for (int c = 0; c < CHUNKS; ++c)
    s += Epart[(size_t)(bb*CHUNKS + c) * (NK*NDIM) + o];
  out[i] = s - asum[bb*NK + k] * Cw[k*NDIM + d];
}

// ---- out = E_acc - asum*C  (atomic-fallback mode) ----
__global__ void finalize_atomic(const float* __restrict__ E_acc,
                                const float* __restrict__ asum,
                                const float* __restrict__ Cw,
                                float* __restrict__ out) {
  const int i = blockIdx.x * 256 + threadIdx.x;
  const int d = i & 255;
  const int k = (i >> 8) & 63;
  const int bb = i >> 14;
  out[i] = E_acc[i] - asum[bb*NK + k] * Cw[k*NDIM + d];
}

extern "C" void kernel_launch(void* const* d_in, const int* in_sizes, int n_in,
                              void* d_out, int out_size, void* d_ws, size_t ws_size,
                              hipStream_t stream) {
  const float* X     = (const float*)d_in[0];
  const float* Cw    = (const float*)d_in[1];
  const float* scale = (const float*)d_in[2];
  float* out = (float*)d_out;

  const bool partials = ws_size >= (size_t)WS_NEED_F * sizeof(float);
  float* wsf = (float*)d_ws;

  if (partials) {
    float* Epart = wsf;
    float* Apart = Epart + WS_EPART_F;
    float* asum  = Apart + WS_APART_F;
    float* c2    = asum + WS_ASUM_F;
    half2_t* Ch  = (half2_t*)(c2 + NK);
    // all partial slots fully written every call: no memset needed
    c2ch_kernel<<<1, 256, 0, stream>>>(Cw, c2, Ch);
    encode_main<<<GRID, 256, 0, stream>>>(X, Ch, scale, c2, Epart, Apart, 1);
    asum_reduce_kernel<<<4, 256, 0, stream>>>(Apart, asum);
    finalize_partials<<<(NB*NK*NDIM)/256, 256, 0, stream>>>(Epart, asum, Cw, out);
  } else {
    float* E_acc = wsf;                         // [NB][NK][NDIM]
    float* asum  = E_acc + NB*NK*NDIM;          // [NB][NK]
    float* c2    = asum + NB*NK;
    half2_t* Ch  = (half2_t*)(c2 + NK);
    hipMemsetAsync(d_ws, 0, (size_t)(NB*NK*NDIM + NB*NK) * sizeof(float), stream);
    c2ch_kernel<<<1, 256, 0, stream>>>(Cw, c2, Ch);
    encode_main<<<GRID, 256, 0, stream>>>(X, Ch, scale, c2, E_acc, asum, 0);
    finalize_atomic<<<(NB*NK*NDIM)/256, 256, 0, stream>>>(E_acc, asum, Cw, out);
  }
}

// Round 3
// 701.063 us; speedup vs baseline: 1.7124x; 1.7124x over previous
//
#include <hip/hip_runtime.h>

// Problem constants (fixed by the reference: B=16, D=256, K=64, H=W=96)
#define NDIM  256          // feature dim D
#define NK    64           // codewords K
#define NPIX  9216         // H*W
#define NB    16           // batch
#define TN    64           // pixels per tile (== wavefront size: lane <-> pixel)
#define NT    3            // tiles per block
#define CHUNKS 48          // NPIX / (TN*NT)
#define GRID  (NB * CHUNKS)   // 768 = exactly 3 blocks/CU on 256 CUs

typedef _Float16 half2_t __attribute__((ext_vector_type(2)));
typedef _Float16 half8_t __attribute__((ext_vector_type(8)));

__device__ __forceinline__ float fdot2(half2_t a, half2_t b, float c) {
  // v_dot2_f32_f16: 2 f16 MACs, fp32 accumulate
  return __builtin_amdgcn_fdot2(a, b, c, false);
}

// ws layout (floats), partials mode:
//   Epart   [GRID][NK*NDIM]   = 12,582,912
//   Apart   [GRID][NK]        = 49,152
//   asum    [NB][NK]          = 1,024
//   c2      [NK]              = 64
//   Ch      [NK][NDIM/2] u32  = 8,192 (half2-packed codewords)
#define WS_EPART_F   (GRID * NK * NDIM)
#define WS_APART_F   (GRID * NK)
#define WS_ASUM_F    (NB * NK)
#define WS_NEED_F    (WS_EPART_F + WS_APART_F + WS_ASUM_F + NK + NK * (NDIM/2))

// ---- c2[k] = sum_d C[k][d]^2, and Ch = half2-packed codewords (once, tiny) ----
__global__ void c2ch_kernel(const float* __restrict__ Cw, float* __restrict__ c2,
                            half2_t* __restrict__ Ch) {
  __shared__ float tmp[256];
  const int t = threadIdx.x;
  const int k = t >> 2, q = t & 3;
  float s = 0.f;
  const float* row = Cw + k * NDIM + q * 64;
  for (int i = 0; i < 64; ++i) { float v = row[i]; s += v * v; }
  tmp[t] = s;
  // pack codewords: 64*128 half2, 32 per thread
  for (int j = 0; j < 32; ++j) {
    const int idx = t * 32 + j;
    const float2 v = *(const float2*)(Cw + 2 * idx);
    half2_t h; h.x = (_Float16)v.x; h.y = (_Float16)v.y;
    Ch[idx] = h;
  }
  __syncthreads();
  if (t < NK) c2[t] = tmp[4*t] + tmp[4*t+1] + tmp[4*t+2] + tmp[4*t+3];
}

// ---- fused: stage -> distances (f16 dot2) -> softmax -> aggregation ----
// block = 256 threads = 4 waves; grid = 768 (3 blocks/CU, LDS-capped).
// NOTE: __launch_bounds__(256,2) is load-bearing: (256,3) made the compiler
// clamp to 84 VGPRs and spill eacc[64] to scratch -> 4.9 GB HBM RMW (R2).
__global__ __launch_bounds__(256, 2) void encode_main(
    const float* __restrict__ X, const half2_t* __restrict__ Ch,
    const float* __restrict__ scale, const float* __restrict__ c2,
    float* __restrict__ Eout, float* __restrict__ Aout, int mode)
{
  // Xtd rows 144 B (16B-aligned, stride 36 dwords): phase-3 b128 reads hit
  // disjoint bank quads; phase-1 u16 reads are 2-lane/dword broadcasts (free)
  __shared__ _Float16 Xtd[NDIM][72];   // f16 X tile, [d][pixel]  (36.9 KB)
  __shared__ _Float16 Al[NK][72];      // softmax weights [k][pix] ( 9.2 KB)
  __shared__ float    red[4][TN];      // cross-wave softmax scratch (1 KB)

  const int tid  = threadIdx.x;
  const int w    = __builtin_amdgcn_readfirstlane(tid >> 6); // wave id 0..3
  const int lane = tid & 63;                                  // pixel in tile
  const int b      = blockIdx.x / CHUNKS;
  const int chunk  = blockIdx.x % CHUNKS;
  const int n_base = chunk * (TN * NT);
  const float* Xb  = X + (size_t)b * NDIM * NPIX;
  const int kbase  = w * 16;     // this wave's k-slab (wave-uniform)
  const int ka     = tid >> 2;   // aggregation: codeword 0..63
  const int dsl    = tid & 3;    // aggregation: d interleave 0..3
  const int np     = tid & 31;   // staging: pixel-pair index
  const int dslab  = tid >> 5;   // staging: d-slab of 32

  float eacc[64];                // E partial [ka][d = 32c+4j+dsl]
#pragma unroll
  for (int i = 0; i < 64; ++i) eacc[i] = 0.f;
  float asum_acc = 0.f;          // sum_n A[n][k=tid] (threads 0..63)

  for (int t = 0; t < NT; ++t) {
    __syncthreads();             // prev tile's phase-3 reads done
    const int n0 = n_base + t * TN;

    // ---- stage: X fetched once, f16-packed pixel pairs ----
    {
      const float* Xg = Xb + (size_t)(dslab * 32) * NPIX + n0 + 2 * np;
#pragma unroll 4
      for (int i = 0; i < 32; ++i) {
        const float2 v = *(const float2*)(Xg + (size_t)i * NPIX);
        half2_t h; h.x = (_Float16)v.x; h.y = (_Float16)v.y;
        *(half2_t*)&Xtd[dslab * 32 + i][2 * np] = h;
      }
    }
    __syncthreads();

    // ---- phase 1: xc + x^2 from LDS, f16 dot2, uniform codewords ----
    // acc[] doubles as the softmax-logit array afterwards (register economy)
    float acc[16];
#pragma unroll
    for (int i = 0; i < 16; ++i) acc[i] = 0.f;
    float xsq = 0.f;
#pragma unroll 2
    for (int dp = 0; dp < NDIM / 2; ++dp) {
      half2_t h; h.x = Xtd[2*dp][lane]; h.y = Xtd[2*dp+1][lane];
      xsq = fdot2(h, h, xsq);
#pragma unroll
      for (int kk = 0; kk < 16; ++kk)
        acc[kk] = fdot2(h, Ch[(kbase + kk) * (NDIM/2) + dp], acc[kk]);
    }

    // ---- phase 2: softmax over k (64 values live across the 4 waves) ----
    float m = -3.0e38f;
#pragma unroll
    for (int kk = 0; kk < 16; ++kk) {
      const float s = scale[kbase+kk] * (xsq - 2.f*acc[kk] + c2[kbase+kk]);
      acc[kk] = s; m = fmaxf(m, s);
    }
    red[w][lane] = m;
    __syncthreads();
    m = fmaxf(fmaxf(red[0][lane], red[1][lane]),
              fmaxf(red[2][lane], red[3][lane]));
    float psum = 0.f;
#pragma unroll
    for (int kk = 0; kk < 16; ++kk) {
      const float p = __expf(acc[kk] - m); acc[kk] = p; psum += p;
    }
    __syncthreads();             // all max-reads done before reuse
    red[w][lane] = psum;
    __syncthreads();
    const float tot  = red[0][lane] + red[1][lane] + red[2][lane] + red[3][lane];
    const float rinv = 1.f / tot;
#pragma unroll
    for (int kk = 0; kk < 16; ++kk)
      Al[kbase+kk][lane] = (_Float16)(acc[kk] * rinv);
    __syncthreads();             // Al visible to aggregation

    // ---- phase 3: E[ka][d] += sum_l A[ka][l] * X[d][l]  (f16 dot2) ----
    for (int lc = 0; lc < 8; ++lc) {
      const int l0 = lc * 8;
      const half8_t av = *(const half8_t*)&Al[ka][l0];
      const half2_t a0 = __builtin_shufflevector(av, av, 0, 1);
      const half2_t a1 = __builtin_shufflevector(av, av, 2, 3);
      const half2_t a2 = __builtin_shufflevector(av, av, 4, 5);
      const half2_t a3 = __builtin_shufflevector(av, av, 6, 7);
#pragma unroll
      for (int c = 0; c < 8; ++c) {
#pragma unroll
        for (int j = 0; j < 8; ++j) {
          const int d = c*32 + j*4 + dsl;
          const half8_t xv = *(const half8_t*)&Xtd[d][l0];
          float e = eacc[c*8+j];
          e = fdot2(__builtin_shufflevector(xv, xv, 0, 1), a0, e);
          e = fdot2(__builtin_shufflevector(xv, xv, 2, 3), a1, e);
          e = fdot2(__builtin_shufflevector(xv, xv, 4, 5), a2, e);
          e = fdot2(__builtin_shufflevector(xv, xv, 6, 7), a3, e);
          eacc[c*8+j] = e;
        }
      }
      if (tid < NK) {            // asum for codeword row `tid`
        const half8_t sv = *(const half8_t*)&Al[tid][l0];
        const half2_t one = {(_Float16)1.f, (_Float16)1.f};
        asum_acc = fdot2(__builtin_shufflevector(sv, sv, 0, 1), one, asum_acc);
        asum_acc = fdot2(__builtin_shufflevector(sv, sv, 2, 3), one, asum_acc);
        asum_acc = fdot2(__builtin_shufflevector(sv, sv, 4, 5), one, asum_acc);
        asum_acc = fdot2(__builtin_shufflevector(sv, sv, 6, 7), one, asum_acc);
      }
    }
  }

  // ---- epilogue ----
  if (mode) {
    // non-atomic per-block partial (L2-merged streaming writes)
    float* Ebk = Eout + (size_t)blockIdx.x * (NK*NDIM) + ka * NDIM;
#pragma unroll
    for (int c = 0; c < 8; ++c)
#pragma unroll
      for (int j = 0; j < 8; ++j)
        Ebk[c*32 + j*4 + dsl] = eacc[c*8+j];
    if (tid < NK) Aout[blockIdx.x * NK + tid] = asum_acc;
  } else {
    float* Ebk = Eout + ((size_t)b * NK + ka) * NDIM;
#pragma unroll
    for (int c = 0; c < 8; ++c)
#pragma unroll
      for (int j = 0; j < 8; ++j)
        atomicAdd(&Ebk[c*32 + j*4 + dsl], eacc[c*8+j]);
    if (tid < NK) atomicAdd(&Aout[b*NK + tid], asum_acc);
  }
}

// ---- asum[b][k] = sum_c Apart[(b*CHUNKS+c)][k] ----
__global__ void asum_reduce_kernel(const float* __restrict__ Apart,
                                   float* __restrict__ asum) {
  const int i = blockIdx.x * 256 + threadIdx.x;   // 0..1023: b = i>>6, k = i&63
  const int bb = i >> 6, k = i & 63;
  float s = 0.f;
  for (int c = 0; c < CHUNKS; ++c) s += Apart[(bb*CHUNKS + c)*NK + k];
  asum[i] = s;
}

// ---- out = sum_c Epart - asum*C  (partials mode) ----
__global__ void finalize_partials(const float* __restrict__ Epart,
                                  const float* __restrict__ asum,
                                  const float* __restrict__ Cw,
                                  float* __restrict__ out) {
  const int i = blockIdx.x * 256 + threadIdx.x;
  const int bb = i >> 14;            // batch
  const int o  = i & 16383;          // k*256+d within batch
  const int k  = o >> 8, d = i & 255;
  float s = 0.f;
#pragma unroll 4
  for (int c = 0; c < CHUNKS; ++c)
    s += Epart[(size_t)(bb*CHUNKS + c) * (NK*NDIM) + o];
  out[i] = s - asum[bb*NK + k] * Cw[k*NDIM + d];
}

// ---- out = E_acc - asum*C  (atomic-fallback mode) ----
__global__ void finalize_atomic(const float* __restrict__ E_acc,
                                const float* __restrict__ asum,
                                const float* __restrict__ Cw,
                                float* __restrict__ out) {
  const int i = blockIdx.x * 256 + threadIdx.x;
  const int d = i & 255;
  const int k = (i >> 8) & 63;
  const int bb = i >> 14;
  out[i] = E_acc[i] - asum[bb*NK + k] * Cw[k*NDIM + d];
}

extern "C" void kernel_launch(void* const* d_in, const int* in_sizes, int n_in,
                              void* d_out, int out_size, void* d_ws, size_t ws_size,
                              hipStream_t stream) {
  const float* X     = (const float*)d_in[0];
  const float* Cw    = (const float*)d_in[1];
  const float* scale = (const float*)d_in[2];
  float* out = (float*)d_out;

  const bool partials = ws_size >= (size_t)WS_NEED_F * sizeof(float);
  float* wsf = (float*)d_ws;

  if (partials) {
    float* Epart = wsf;
    float* Apart = Epart + WS_EPART_F;
    float* asum  = Apart + WS_APART_F;
    float* c2    = asum + WS_ASUM_F;
    half2_t* Ch  = (half2_t*)(c2 + NK);
    // all partial slots fully written every call: no memset needed
    c2ch_kernel<<<1, 256, 0, stream>>>(Cw, c2, Ch);
    encode_main<<<GRID, 256, 0, stream>>>(X, Ch, scale, c2, Epart, Apart, 1);
    asum_reduce_kernel<<<4, 256, 0, stream>>>(Apart, asum);
    finalize_partials<<<(NB*NK*NDIM)/256, 256, 0, stream>>>(Epart, asum, Cw, out);
  } else {
    float* E_acc = wsf;                         // [NB][NK][NDIM]
    float* asum  = E_acc + NB*NK*NDIM;          // [NB][NK]
    float* c2    = asum + NB*NK;
    half2_t* Ch  = (half2_t*)(c2 + NK);
    hipMemsetAsync(d_ws, 0, (size_t)(NB*NK*NDIM + NB*NK) * sizeof(float), stream);
    c2ch_kernel<<<1, 256, 0, stream>>>(Cw, c2, Ch);
    encode_main<<<GRID, 256, 0, stream>>>(X, Ch, scale, c2, E_acc, asum, 0);
    finalize_atomic<<<(NB*NK*NDIM)/256, 256, 0, stream>>>(E_acc, asum, Cw, out);
  }
}

// Round 4
// 318.292 us; speedup vs baseline: 3.7717x; 2.2026x over previous
//
#include <hip/hip_runtime.h>

// Problem constants (fixed by the reference: B=16, D=256, K=64, H=W=96)
#define NDIM  256          // feature dim D
#define NK    64           // codewords K
#define NPIX  9216         // H*W
#define NB    16           // batch
#define TN    64           // pixels per tile (== wavefront size: lane <-> pixel)
#define TILES_PB 144       // NPIX / TN, pixel-tiles per batch
#define WMAX  48           // max writers per batch (grid 768 = 3 blocks/CU)

typedef _Float16 half2_t __attribute__((ext_vector_type(2)));
typedef _Float16 half8_t __attribute__((ext_vector_type(8)));

__device__ __forceinline__ float fdot2(half2_t a, half2_t b, float c) {
  // v_dot2_f32_f16: 2 f16 MACs, fp32 accumulate
  return __builtin_amdgcn_fdot2(a, b, c, false);
}

// ws layout (float offsets), shared by both modes:
//   Ch    [NK][NDIM/2] half2   8192 f
//   c2    [NK]                   64 f
//   asum  [NB][NK]             1024 f
//   Apart [NB*WMAX][NK]       49152 f   (partials mode)
//   EpartH [NB*W][NK*NDIM] f16          (partials mode, W adaptive)
//   E_acc [NB][NK*NDIM] f32             (atomic fallback, aliases Apart..)
#define OFF_CH     0
#define OFF_C2     (NK * NDIM / 2)
#define OFF_ASUM   (OFF_C2 + NK)
#define OFF_APART  (OFF_ASUM + NB * NK)
#define OFF_EPART  (OFF_APART + NB * WMAX * NK)

// ---- c2[k] = sum_d C[k][d]^2, and Ch = half2-packed codewords (once, tiny) ----
__global__ void c2ch_kernel(const float* __restrict__ Cw, float* __restrict__ c2,
                            half2_t* __restrict__ Ch) {
  __shared__ float tmp[256];
  const int t = threadIdx.x;
  const int k = t >> 2, q = t & 3;
  float s = 0.f;
  const float* row = Cw + k * NDIM + q * 64;
  for (int i = 0; i < 64; ++i) { float v = row[i]; s += v * v; }
  tmp[t] = s;
  for (int j = 0; j < 32; ++j) {          // pack 64*128 half2, 32/thread
    const int idx = t * 32 + j;
    const float2 v = *(const float2*)(Cw + 2 * idx);
    half2_t h; h.x = (_Float16)v.x; h.y = (_Float16)v.y;
    Ch[idx] = h;
  }
  __syncthreads();
  if (t < NK) c2[t] = tmp[4*t] + tmp[4*t+1] + tmp[4*t+2] + tmp[4*t+3];
}

// ---- fused: stage -> distances -> softmax -> aggregation ----
// grid = NB*W blocks; block (b,w) handles tiles t = w, w+W, ... < 144.
// Phase 3 is register-tiled 8k x 8d per thread: thread=(kg=tid>>5, dg=tid&31),
// k = kg*8+i, d = j*32+dg. A-frags broadcast (all dg same addr); X-frags hit
// the 4-lane/bank-quad structural floor. 128 b128/thread-tile vs 512 before.
// NOTE: __launch_bounds__(256,2) is load-bearing: (256,3) clamped VGPRs to 84
// and spilled eacc[64] -> 4.9 GB scratch RMW (R2).
__global__ __launch_bounds__(256, 2) void encode_main(
    const float* __restrict__ X, const half2_t* __restrict__ Ch,
    const float* __restrict__ scale, const float* __restrict__ c2,
    void* __restrict__ Eout, float* __restrict__ Aout, int W, int mode)
{
  __shared__ _Float16 Xtd[NDIM][72];   // f16 X tile, [d][pixel]  (36.9 KB)
  __shared__ _Float16 Al[NK][72];      // softmax weights [k][pix] ( 9.2 KB)
  __shared__ float    red[4][TN];      // cross-wave softmax scratch (1 KB)

  const int tid  = threadIdx.x;
  const int w4   = __builtin_amdgcn_readfirstlane(tid >> 6); // wave id 0..3
  const int lane = tid & 63;                                  // pixel in tile
  const int b    = blockIdx.x / W;
  const int wid  = blockIdx.x % W;     // writer slot within batch
  const float* Xb  = X + (size_t)b * NDIM * NPIX;
  const int kbase  = w4 * 16;    // phase-1: this wave's k-slab (uniform)
  const int kg     = tid >> 5;   // phase-3: k-group (8 rows)
  const int dg     = tid & 31;   // phase-3: d lane within 32
  const int np     = tid & 31;   // staging: pixel-pair index
  const int dslab  = tid >> 5;   // staging: d-slab of 32

  float eacc[64];                // E partial [i][j]: k=kg*8+i, d=j*32+dg
#pragma unroll
  for (int i = 0; i < 64; ++i) eacc[i] = 0.f;
  float asum_acc = 0.f;          // sum_n A[n][k=tid] (threads 0..63)

  for (int t = wid; t < TILES_PB; t += W) {
    __syncthreads();             // prev tile's phase-3 reads done
    const int n0 = t * TN;

    // ---- stage: X fetched once, f16-packed pixel pairs ----
    {
      const float* Xg = Xb + (size_t)(dslab * 32) * NPIX + n0 + 2 * np;
#pragma unroll 4
      for (int i = 0; i < 32; ++i) {
        const float2 v = *(const float2*)(Xg + (size_t)i * NPIX);
        half2_t h; h.x = (_Float16)v.x; h.y = (_Float16)v.y;
        *(half2_t*)&Xtd[dslab * 32 + i][2 * np] = h;
      }
    }
    __syncthreads();

    // ---- phase 1: xc + x^2 from LDS, f16 dot2, uniform codewords ----
    float acc[16];               // doubles as softmax logits (reg economy)
#pragma unroll
    for (int i = 0; i < 16; ++i) acc[i] = 0.f;
    float xsq = 0.f;
#pragma unroll 2
    for (int dp = 0; dp < NDIM / 2; ++dp) {
      half2_t h; h.x = Xtd[2*dp][lane]; h.y = Xtd[2*dp+1][lane];
      xsq = fdot2(h, h, xsq);
#pragma unroll
      for (int kk = 0; kk < 16; ++kk)
        acc[kk] = fdot2(h, Ch[(kbase + kk) * (NDIM/2) + dp], acc[kk]);
    }

    // ---- phase 2: softmax over k (64 values across the 4 waves) ----
    float m = -3.0e38f;
#pragma unroll
    for (int kk = 0; kk < 16; ++kk) {
      const float s = scale[kbase+kk] * (xsq - 2.f*acc[kk] + c2[kbase+kk]);
      acc[kk] = s; m = fmaxf(m, s);
    }
    red[w4][lane] = m;
    __syncthreads();
    m = fmaxf(fmaxf(red[0][lane], red[1][lane]),
              fmaxf(red[2][lane], red[3][lane]));
    float psum = 0.f;
#pragma unroll
    for (int kk = 0; kk < 16; ++kk) {
      const float p = __expf(acc[kk] - m); acc[kk] = p; psum += p;
    }
    __syncthreads();
    red[w4][lane] = psum;
    __syncthreads();
    const float tot  = red[0][lane] + red[1][lane] + red[2][lane] + red[3][lane];
    const float rinv = 1.f / tot;
#pragma unroll
    for (int kk = 0; kk < 16; ++kk)
      Al[kbase+kk][lane] = (_Float16)(acc[kk] * rinv);
    __syncthreads();             // Al visible to aggregation

    // ---- phase 3: eacc[i][j] += sum_l A[kg*8+i][l] * X[j*32+dg][l] ----
    for (int lc = 0; lc < 8; ++lc) {
      const int l0 = lc * 8;
      half8_t af[8];
#pragma unroll
      for (int i = 0; i < 8; ++i)
        af[i] = *(const half8_t*)&Al[kg*8 + i][l0];   // broadcast across dg
#pragma unroll
      for (int j = 0; j < 8; ++j) {
        const half8_t xv = *(const half8_t*)&Xtd[j*32 + dg][l0];
        const half2_t x0 = __builtin_shufflevector(xv, xv, 0, 1);
        const half2_t x1 = __builtin_shufflevector(xv, xv, 2, 3);
        const half2_t x2 = __builtin_shufflevector(xv, xv, 4, 5);
        const half2_t x3 = __builtin_shufflevector(xv, xv, 6, 7);
#pragma unroll
        for (int i = 0; i < 8; ++i) {
          float e = eacc[i*8 + j];
          e = fdot2(__builtin_shufflevector(af[i], af[i], 0, 1), x0, e);
          e = fdot2(__builtin_shufflevector(af[i], af[i], 2, 3), x1, e);
          e = fdot2(__builtin_shufflevector(af[i], af[i], 4, 5), x2, e);
          e = fdot2(__builtin_shufflevector(af[i], af[i], 6, 7), x3, e);
          eacc[i*8 + j] = e;
        }
      }
      if (tid < NK) {            // asum for codeword row `tid`
        const half8_t sv = *(const half8_t*)&Al[tid][l0];
        const half2_t one = {(_Float16)1.f, (_Float16)1.f};
        asum_acc = fdot2(__builtin_shufflevector(sv, sv, 0, 1), one, asum_acc);
        asum_acc = fdot2(__builtin_shufflevector(sv, sv, 2, 3), one, asum_acc);
        asum_acc = fdot2(__builtin_shufflevector(sv, sv, 4, 5), one, asum_acc);
        asum_acc = fdot2(__builtin_shufflevector(sv, sv, 6, 7), one, asum_acc);
      }
    }
  }

  // ---- epilogue ----
  if (mode) {
    // non-atomic per-block f16 partial (streaming, L2/L3-merged)
    _Float16* Ebk = (_Float16*)Eout + (size_t)blockIdx.x * (NK * NDIM);
#pragma unroll
    for (int i = 0; i < 8; ++i)
#pragma unroll
      for (int j = 0; j < 8; ++j)
        Ebk[(kg*8 + i) * NDIM + j*32 + dg] = (_Float16)eacc[i*8 + j];
    if (tid < NK) Aout[blockIdx.x * NK + tid] = asum_acc;
  } else {
    float* Ebk = (float*)Eout + ((size_t)b * NK + kg*8) * NDIM;
#pragma unroll
    for (int i = 0; i < 8; ++i)
#pragma unroll
      for (int j = 0; j < 8; ++j)
        atomicAdd(&Ebk[i * NDIM + j*32 + dg], eacc[i*8 + j]);
    if (tid < NK) atomicAdd(&Aout[b*NK + tid], asum_acc);
  }
}

// ---- asum[b][k] = sum_w Apart[(b*W+w)][k] ----
__global__ void asum_reduce_kernel(const float* __restrict__ Apart,
                                   float* __restrict__ asum, int W) {
  const int i = blockIdx.x * 256 + threadIdx.x;   // 0..1023
  const int bb = i >> 6, k = i & 63;
  float s = 0.f;
  for (int w = 0; w < W; ++w) s += Apart[(bb*W + w)*NK + k];
  asum[i] = s;
}

// ---- out = sum_w Epart(f16) - asum*C  (partials mode) ----
__global__ void finalize_partials(const _Float16* __restrict__ EpartH,
                                  const float* __restrict__ asum,
                                  const float* __restrict__ Cw,
                                  float* __restrict__ out, int W) {
  const int i = blockIdx.x * 256 + threadIdx.x;
  const int bb = i >> 14;            // batch
  const int o  = i & 16383;          // k*256+d within batch
  const int k  = o >> 8, d = i & 255;
  float s = 0.f;
  for (int w = 0; w < W; ++w)
    s += (float)EpartH[((size_t)(bb*W + w) << 14) + o];
  out[i] = s - asum[bb*NK + k] * Cw[k*NDIM + d];
}

// ---- out = E_acc - asum*C  (atomic-fallback mode) ----
__global__ void finalize_atomic(const float* __restrict__ E_acc,
                                const float* __restrict__ asum,
                                const float* __restrict__ Cw,
                                float* __restrict__ out) {
  const int i = blockIdx.x * 256 + threadIdx.x;
  const int d = i & 255;
  const int k = (i >> 8) & 63;
  const int bb = i >> 14;
  out[i] = E_acc[i] - asum[bb*NK + k] * Cw[k*NDIM + d];
}

extern "C" void kernel_launch(void* const* d_in, const int* in_sizes, int n_in,
                              void* d_out, int out_size, void* d_ws, size_t ws_size,
                              hipStream_t stream) {
  const float* X     = (const float*)d_in[0];
  const float* Cw    = (const float*)d_in[1];
  const float* scale = (const float*)d_in[2];
  float* out = (float*)d_out;

  float* wsf = (float*)d_ws;
  half2_t* Ch  = (half2_t*)(wsf + OFF_CH);
  float* c2    = wsf + OFF_C2;
  float* asum  = wsf + OFF_ASUM;
  float* Apart = wsf + OFF_APART;

  // writers per batch, sized to ws: each unit of W costs NB*NK*NDIM f16 bytes
  int W = 0;
  const size_t ovh = (size_t)OFF_EPART * sizeof(float);
  if (ws_size > ovh)
    W = (int)((ws_size - ovh) / ((size_t)NB * NK * NDIM * sizeof(_Float16)));
  if (W > WMAX) W = WMAX;

  c2ch_kernel<<<1, 256, 0, stream>>>(Cw, c2, Ch);
  if (W >= 8) {
    _Float16* EpartH = (_Float16*)(wsf + OFF_EPART);
    encode_main<<<NB * W, 256, 0, stream>>>(X, Ch, scale, c2, EpartH, Apart, W, 1);
    asum_reduce_kernel<<<4, 256, 0, stream>>>(Apart, asum, W);
    finalize_partials<<<(NB*NK*NDIM)/256, 256, 0, stream>>>(EpartH, asum, Cw, out, W);
  } else {
    // tiny-ws fallback: fp32 atomics (known-correct path). E_acc aliases Apart+
    float* E_acc = wsf + OFF_APART;              // 1 MB, fits round-1 ws floor
    hipMemsetAsync(asum, 0, (size_t)(NB*NK + NB*NK*NDIM) * sizeof(float) +
                   ((char*)E_acc - (char*)(asum + NB*NK)), stream);
    encode_main<<<NB * WMAX, 256, 0, stream>>>(X, Ch, scale, c2, E_acc, asum, WMAX, 0);
    finalize_atomic<<<(NB*NK*NDIM)/256, 256, 0, stream>>>(E_acc, asum, Cw, out);
  }
}

// Round 5
// 253.616 us; speedup vs baseline: 4.7335x; 1.2550x over previous
//
#include <hip/hip_runtime.h>

// Problem constants (fixed by the reference: B=16, D=256, K=64, H=W=96)
#define NDIM  256
#define NK    64
#define NPIX  9216
#define NB    16
#define TN    64           // pixels per tile
#define NW    48           // writer blocks per batch
#define TPB   3            // tiles per block = 144/NW
#define TILES_PB 144
#define GRID  (NB*NW)      // 768

typedef _Float16 half2_t __attribute__((ext_vector_type(2)));
typedef _Float16 half8_t __attribute__((ext_vector_type(8)));
typedef float    f32x4  __attribute__((ext_vector_type(4)));

__device__ __forceinline__ float fdot2(half2_t a, half2_t b, float c) {
  return __builtin_amdgcn_fdot2(a, b, c, false);
}

// ws layout (float offsets):
//   ChH   f16[NK][NDIM]          (8192 floats)
//   c2    [NK]
//   asum  [NB][NK]
//   Apart [GRID][NK]
//   EpartH f16[GRID][NK*NDIM]    (partials) | E_acc f32[NB][NK*NDIM] (fallback)
#define OFF_CH     0
#define OFF_C2     (NK * NDIM / 2)
#define OFF_ASUM   (OFF_C2 + NK)
#define OFF_APART  (OFF_ASUM + NB * NK)
#define OFF_EPART  (OFF_APART + GRID * NK)
#define WS_NEED    ((size_t)OFF_EPART * 4 + (size_t)GRID * NK * NDIM * 2)

// ---- c2[k] + f16 codeword pack; 64 blocks x 64 threads (R4's 1-block
// version was latency-bound on a single CU — likely ~100 us of the gap) ----
__global__ void c2ch_kernel(const float* __restrict__ Cw, float* __restrict__ c2,
                            _Float16* __restrict__ ChH) {
  const int k = blockIdx.x, t = threadIdx.x;
  const float4 v = *(const float4*)(Cw + k * NDIM + 4 * t);
  half2_t h0; h0.x = (_Float16)v.x; h0.y = (_Float16)v.y;
  half2_t h1; h1.x = (_Float16)v.z; h1.y = (_Float16)v.w;
  *(half2_t*)&ChH[k * NDIM + 4 * t]     = h0;
  *(half2_t*)&ChH[k * NDIM + 4 * t + 2] = h1;
  float s = v.x*v.x + v.y*v.y + v.z*v.z + v.w*v.w;
#pragma unroll
  for (int o = 32; o; o >>= 1) s += __shfl_down(s, o);
  if (t == 0) c2[k] = s;
}

// ---- fused MFMA kernel ----
// block = 256 = 4 waves; wave w: phase1 k-slab [w*16,w*16+16), phase3 d-slab
// [w*64,w*64+64). X tile in blocked LDS layout Xb[d>>3][p][d&7] so BOTH
// GEMMs' contraction-contiguous operands are b128 reads:
//   GEMM1 (S^T[k][p] = C·X^T, contract d):  A=codewords (regs, tile-invariant),
//        B[d][p]: lane reads 8 consecutive d of one pixel  -> b128
//   GEMM2 (E^T[d][k] = X·A,  contract p):   A[d][p]: 8 u16 gather (4-way),
//        B[p][k] = Al[k][p] row -> b128
// MFMA accumulators live in AGPRs natively (kills R4's accvgpr-shuffle tax).
__global__ __launch_bounds__(256, 2) void encode_main(
    const float* __restrict__ X, const _Float16* __restrict__ ChH,
    const float* __restrict__ scale, const float* __restrict__ c2,
    void* __restrict__ Eout, float* __restrict__ Aout, int mode)
{
  // XbS = Xb[32][66][8] f16 (33,792 B). Row-pad 66 decorrelates banks.
  // Epilogue aliases it as Et[64][264] (same 33,792 B, 16B-aligned rows).
  __shared__ _Float16 XbS[32 * 66 * 8];
  __shared__ _Float16 Al[NK][72];      // softmax weights [k][p] (9,216 B)
  __shared__ float red2[4][TN];        // x^2 partials per d-quarter
  __shared__ float redM[4][TN];        // per-wave softmax max
  __shared__ float redS[4][TN];        // per-wave softmax sum

  const int tid  = threadIdx.x;
  const int w    = __builtin_amdgcn_readfirstlane(tid >> 6);
  const int lane = tid & 63;
  const int m    = lane & 15, quad = lane >> 4;
  const int b    = blockIdx.x / NW;
  const int wid  = blockIdx.x % NW;
  const float* Xbase = X + (size_t)b * NDIM * NPIX;
  const int kbase = w * 16;

  // phase-1 A-frags (codewords): tile-invariant -> load ONCE into registers.
  // lane holds C[kbase+m][d = 32ks + quad*8 + j]  (A layout: A[m][k=quad*8+j])
  half8_t af1[8];
#pragma unroll
  for (int ks = 0; ks < 8; ++ks)
    af1[ks] = *(const half8_t*)(ChH + (kbase + m) * NDIM + ks * 32 + quad * 8);

  // per-lane scale/c2 for its 4 output k-rows (k = kbase + quad*4 + r)
  const float4 scv = *(const float4*)(scale + kbase + quad * 4);
  const float4 c2v = *(const float4*)(c2 + kbase + quad * 4);
  const float sc[4] = {scv.x, scv.y, scv.z, scv.w};
  const float sq[4] = {scv.x * c2v.x, scv.y * c2v.y, scv.z * c2v.z, scv.w * c2v.w};

  f32x4 acc_e[4][4];                   // E^T frags [dt][kt] -> AGPRs
#pragma unroll
  for (int i = 0; i < 4; ++i)
#pragma unroll
    for (int j = 0; j < 4; ++j)
      acc_e[i][j] = (f32x4){0.f, 0.f, 0.f, 0.f};
  float asum_acc = 0.f;

  for (int tt = 0; tt < TPB; ++tt) {
    const int n0 = (wid + tt * NW) * TN;
    __syncthreads();                   // B1: prev tile's phase-3 reads done

    // ---- stage: wave w loads d-slab [w*64..+64) for all 64 pixels ----
    {
      const float* Xg = Xbase + (size_t)(w * 64) * NPIX + n0 + lane;
      float xsq = 0.f;
#pragma unroll
      for (int g = 0; g < 8; ++g) {
        float xv[8];
#pragma unroll
        for (int i = 0; i < 8; ++i) xv[i] = Xg[(size_t)(g * 8 + i) * NPIX];
        half8_t hv;
#pragma unroll
        for (int i = 0; i < 8; ++i) { hv[i] = (_Float16)xv[i]; xsq += xv[i] * xv[i]; }
        *(half8_t*)&XbS[((w * 8 + g) * 66 + lane) * 8] = hv;
      }
      red2[w][lane] = xsq;
    }
    __syncthreads();                   // B2: Xb + red2 visible

    // ---- phase 1 MFMA: S^T[k 16][p 64] per wave ----
    f32x4 accs[4];
#pragma unroll
    for (int nt = 0; nt < 4; ++nt) accs[nt] = (f32x4){0.f, 0.f, 0.f, 0.f};
#pragma unroll
    for (int ks = 0; ks < 8; ++ks) {
#pragma unroll
      for (int nt = 0; nt < 4; ++nt) {
        const half8_t bf = *(const half8_t*)&XbS[((ks * 4 + quad) * 66 + nt * 16 + m) * 8];
        accs[nt] = __builtin_amdgcn_mfma_f32_16x16x32_f16(af1[ks], bf, accs[nt], 0, 0, 0);
      }
    }

    // ---- phase 2: softmax over k; in-wave shfl reduce + 1 LDS exchange ----
    float e[4][4], mw[4];
#pragma unroll
    for (int nt = 0; nt < 4; ++nt) {
      const int p = nt * 16 + m;
      const float x2p = red2[0][p] + red2[1][p] + red2[2][p] + red2[3][p];
      float L[4];
      float mx = -3.0e38f;
#pragma unroll
      for (int r = 0; r < 4; ++r) {
        L[r] = sc[r] * x2p - 2.f * sc[r] * accs[nt][r] + sq[r];
        mx = fmaxf(mx, L[r]);
      }
      mx = fmaxf(mx, __shfl_xor(mx, 16));   // reduce over quads (same pixel)
      mx = fmaxf(mx, __shfl_xor(mx, 32));
      float s = 0.f;
#pragma unroll
      for (int r = 0; r < 4; ++r) { e[nt][r] = __expf(L[r] - mx); s += e[nt][r]; }
      s += __shfl_xor(s, 16);
      s += __shfl_xor(s, 32);
      mw[nt] = mx;
      if (lane < 16) { redM[w][p] = mx; redS[w][p] = s; }
    }
    __syncthreads();                   // B3: cross-wave max/sum exchange
#pragma unroll
    for (int nt = 0; nt < 4; ++nt) {
      const int p = nt * 16 + m;
      const float M = fmaxf(fmaxf(redM[0][p], redM[1][p]),
                            fmaxf(redM[2][p], redM[3][p]));
      const float T = redS[0][p] * __expf(redM[0][p] - M)
                    + redS[1][p] * __expf(redM[1][p] - M)
                    + redS[2][p] * __expf(redM[2][p] - M)
                    + redS[3][p] * __expf(redM[3][p] - M);
      const float norm = __expf(mw[nt] - M) / T;
#pragma unroll
      for (int r = 0; r < 4; ++r)
        Al[kbase + quad * 4 + r][p] = (_Float16)(e[nt][r] * norm);
    }
    __syncthreads();                   // B4: Al visible

    // ---- phase 3 MFMA: E^T[d 64][k 64] per wave, accumulate across tiles ----
#pragma unroll
    for (int ks = 0; ks < 2; ++ks) {
      half8_t ba[4];
#pragma unroll
      for (int kt = 0; kt < 4; ++kt)   // B[p][k]=Al[k][p] row: b128
        ba[kt] = *(const half8_t*)&Al[kt * 16 + m][ks * 32 + quad * 8];
#pragma unroll
      for (int dt = 0; dt < 4; ++dt) {
        const int c = w * 8 + dt * 2 + (m >> 3);
        const int dlow = m & 7;
        half8_t xa;                    // A[d][p]: 8 u16 gather (~4-way)
#pragma unroll
        for (int j = 0; j < 8; ++j)
          xa[j] = XbS[(c * 66 + ks * 32 + quad * 8 + j) * 8 + dlow];
#pragma unroll
        for (int kt = 0; kt < 4; ++kt)
          acc_e[dt][kt] = __builtin_amdgcn_mfma_f32_16x16x32_f16(xa, ba[kt], acc_e[dt][kt], 0, 0, 0);
      }
    }
    // asum rows (wave 0 only; uniform branch)
    if (tid < NK) {
      const half2_t one = {(_Float16)1.f, (_Float16)1.f};
#pragma unroll
      for (int lc = 0; lc < 8; ++lc) {
        const half8_t sv = *(const half8_t*)&Al[tid][lc * 8];
        asum_acc = fdot2(__builtin_shufflevector(sv, sv, 0, 1), one, asum_acc);
        asum_acc = fdot2(__builtin_shufflevector(sv, sv, 2, 3), one, asum_acc);
        asum_acc = fdot2(__builtin_shufflevector(sv, sv, 4, 5), one, asum_acc);
        asum_acc = fdot2(__builtin_shufflevector(sv, sv, 6, 7), one, asum_acc);
      }
    }
  }

  // ---- epilogue: transpose frags through LDS (XbS dead -> alias as Et) ----
  __syncthreads();
  _Float16* Et = XbS;                  // [64][264], rows 528 B (16B-aligned)
#pragma unroll
  for (int dt = 0; dt < 4; ++dt)
#pragma unroll
    for (int kt = 0; kt < 4; ++kt)
#pragma unroll
      for (int r = 0; r < 4; ++r) {
        // C/D layout: col=lane&15 -> k, row=quad*4+r -> d
        const int k = kt * 16 + m;
        const int d = w * 64 + dt * 16 + quad * 4 + r;
        Et[k * 264 + d] = (_Float16)acc_e[dt][kt][r];
      }
  __syncthreads();
  const int ko = tid >> 2, cq = tid & 3;
  if (mode) {
    _Float16* Ebk = (_Float16*)Eout + (size_t)blockIdx.x * (NK * NDIM);
#pragma unroll
    for (int g = 0; g < 8; ++g)
      *(half8_t*)&Ebk[ko * NDIM + cq * 64 + g * 8] =
          *(const half8_t*)&Et[ko * 264 + cq * 64 + g * 8];
    if (tid < NK) Aout[blockIdx.x * NK + tid] = asum_acc;
  } else {
    float* Ebk = (float*)Eout + (size_t)b * (NK * NDIM);
#pragma unroll
    for (int g = 0; g < 64; ++g)
      atomicAdd(&Ebk[ko * NDIM + cq * 64 + g], (float)Et[ko * 264 + cq * 64 + g]);
    if (tid < NK) atomicAdd(&Aout[b * NK + tid], asum_acc);
  }
}

// ---- asum[b][k] = sum_w Apart[(b*NW+w)][k] ----
__global__ void asum_reduce_kernel(const float* __restrict__ Apart,
                                   float* __restrict__ asum) {
  const int i = blockIdx.x * 256 + threadIdx.x;
  const int bb = i >> 6, k = i & 63;
  float s = 0.f;
  for (int w = 0; w < NW; ++w) s += Apart[(bb * NW + w) * NK + k];
  asum[i] = s;
}

// ---- out = sum_w Epart(f16) - asum*C ----
__global__ void finalize_partials(const _Float16* __restrict__ EpartH,
                                  const float* __restrict__ asum,
                                  const float* __restrict__ Cw,
                                  float* __restrict__ out) {
  const int i = blockIdx.x * 256 + threadIdx.x;
  const int bb = i >> 14;
  const int o  = i & 16383;
  const int k  = o >> 8, d = i & 255;
  float s = 0.f;
#pragma unroll 4
  for (int w = 0; w < NW; ++w)
    s += (float)EpartH[((size_t)(bb * NW + w) << 14) + o];
  out[i] = s - asum[bb * NK + k] * Cw[k * NDIM + d];
}

// ---- out = E_acc - asum*C (atomic-fallback mode) ----
__global__ void finalize_atomic(const float* __restrict__ E_acc,
                                const float* __restrict__ asum,
                                const float* __restrict__ Cw,
                                float* __restrict__ out) {
  const int i = blockIdx.x * 256 + threadIdx.x;
  const int d = i & 255;
  const int k = (i >> 8) & 63;
  const int bb = i >> 14;
  out[i] = E_acc[i] - asum[bb * NK + k] * Cw[k * NDIM + d];
}

extern "C" void kernel_launch(void* const* d_in, const int* in_sizes, int n_in,
                              void* d_out, int out_size, void* d_ws, size_t ws_size,
                              hipStream_t stream) {
  const float* X     = (const float*)d_in[0];
  const float* Cw    = (const float*)d_in[1];
  const float* scale = (const float*)d_in[2];
  float* out = (float*)d_out;

  float* wsf = (float*)d_ws;
  _Float16* ChH = (_Float16*)(wsf + OFF_CH);
  float* c2     = wsf + OFF_C2;
  float* asum   = wsf + OFF_ASUM;
  float* Apart  = wsf + OFF_APART;

  c2ch_kernel<<<NK, 64, 0, stream>>>(Cw, c2, ChH);
  if (ws_size >= WS_NEED) {
    _Float16* EpartH = (_Float16*)(wsf + OFF_EPART);
    encode_main<<<GRID, 256, 0, stream>>>(X, ChH, scale, c2, EpartH, Apart, 1);
    asum_reduce_kernel<<<4, 256, 0, stream>>>(Apart, asum);
    finalize_partials<<<(NB*NK*NDIM)/256, 256, 0, stream>>>(EpartH, asum, Cw, out);
  } else {
    float* E_acc = wsf + OFF_APART;   // fallback: fp32 atomic accumulator
    hipMemsetAsync(wsf + OFF_ASUM, 0,
                   (size_t)(NB*NK + GRID*NK + NB*NK*NDIM) * sizeof(float), stream);
    encode_main<<<GRID, 256, 0, stream>>>(X, ChH, scale, c2, E_acc, asum, 0);
    finalize_atomic<<<(NB*NK*NDIM)/256, 256, 0, stream>>>(E_acc, asum, Cw, out);
  }
}

// Round 6
// 242.958 us; speedup vs baseline: 4.9412x; 1.0439x over previous
//
#include <hip/hip_runtime.h>

// Problem constants (fixed by the reference: B=16, D=256, K=64, H=W=96)
#define NDIM  256
#define NK    64
#define NPIX  9216
#define NB    16
#define TN    64           // pixels per tile
#define NW    48           // writer blocks per batch
#define TPB   3            // tiles per block = 144/NW
#define GRID  (NB*NW)      // 768

typedef _Float16 half2_t __attribute__((ext_vector_type(2)));
typedef _Float16 half8_t __attribute__((ext_vector_type(8)));
typedef float    f32x4  __attribute__((ext_vector_type(4)));

__device__ __forceinline__ float fdot2(half2_t a, half2_t b, float c) {
  return __builtin_amdgcn_fdot2(a, b, c, false);
}

// ws layout (float offsets):
#define OFF_CH     0
#define OFF_C2     (NK * NDIM / 2)
#define OFF_ASUM   (OFF_C2 + NK)
#define OFF_APART  (OFF_ASUM + NB * NK)
#define OFF_EPART  (OFF_APART + GRID * NK)
#define WS_NEED    ((size_t)OFF_EPART * 4 + (size_t)GRID * NK * NDIM * 2)

// ---- c2[k] + f16 codeword pack ----
__global__ void c2ch_kernel(const float* __restrict__ Cw, float* __restrict__ c2,
                            _Float16* __restrict__ ChH) {
  const int k = blockIdx.x, t = threadIdx.x;
  const float4 v = *(const float4*)(Cw + k * NDIM + 4 * t);
  half2_t h0; h0.x = (_Float16)v.x; h0.y = (_Float16)v.y;
  half2_t h1; h1.x = (_Float16)v.z; h1.y = (_Float16)v.w;
  *(half2_t*)&ChH[k * NDIM + 4 * t]     = h0;
  *(half2_t*)&ChH[k * NDIM + 4 * t + 2] = h1;
  float s = v.x*v.x + v.y*v.y + v.z*v.z + v.w*v.w;
#pragma unroll
  for (int o = 32; o; o >>= 1) s += __shfl_down(s, o);
  if (t == 0) c2[k] = s;
}

// ---- fused MFMA kernel with register-prefetch staging pipeline ----
// R5 was latency-bound (MfmaUtil 4%, VALU 12%): the 64 staging loads sat on
// the critical path each tile. Now tile t+1's loads are issued into VGPRs
// right after B2 and consumed next iteration; phase 1-3 (~2K cyc) hides them.
// Costs ~64 VGPRs -> ~216 unified regs; still 2 waves/SIMD (same as R5).
__global__ __launch_bounds__(256, 2) void encode_main(
    const float* __restrict__ X, const _Float16* __restrict__ ChH,
    const float* __restrict__ scale, const float* __restrict__ c2,
    void* __restrict__ Eout, float* __restrict__ Aout, int mode)
{
  __shared__ _Float16 XbS[32 * 66 * 8];   // Xb[d>>3][p][d&7], 33,792 B
  __shared__ _Float16 Al[NK][72];         // softmax weights [k][p]
  __shared__ float red2[4][TN];
  __shared__ float redM[4][TN];
  __shared__ float redS[4][TN];

  const int tid  = threadIdx.x;
  const int w    = __builtin_amdgcn_readfirstlane(tid >> 6);
  const int lane = tid & 63;
  const int m    = lane & 15, quad = lane >> 4;
  const int b    = blockIdx.x / NW;
  const int wid  = blockIdx.x % NW;
  const float* Xbase = X + (size_t)b * NDIM * NPIX;
  const int kbase = w * 16;

  // phase-1 A-frags (codewords): tile-invariant, registers
  half8_t af1[8];
#pragma unroll
  for (int ks = 0; ks < 8; ++ks)
    af1[ks] = *(const half8_t*)(ChH + (kbase + m) * NDIM + ks * 32 + quad * 8);

  const float4 scv = *(const float4*)(scale + kbase + quad * 4);
  const float4 c2v = *(const float4*)(c2 + kbase + quad * 4);
  const float sc[4] = {scv.x, scv.y, scv.z, scv.w};
  const float sq[4] = {scv.x * c2v.x, scv.y * c2v.y, scv.z * c2v.z, scv.w * c2v.w};

  f32x4 acc_e[4][4];
#pragma unroll
  for (int i = 0; i < 4; ++i)
#pragma unroll
    for (int j = 0; j < 4; ++j)
      acc_e[i][j] = (f32x4){0.f, 0.f, 0.f, 0.f};
  float asum_acc = 0.f;

  // ---- prefetch tile 0 into registers ----
  float xv[64];
  {
    const float* Xg = Xbase + (size_t)(w * 64) * NPIX + wid * TN + lane;
#pragma unroll
    for (int i = 0; i < 64; ++i) xv[i] = Xg[(size_t)i * NPIX];
  }

  for (int tt = 0; tt < TPB; ++tt) {
    __syncthreads();                   // B1: prev tile's phase-3 reads done

    // ---- stage from prefetch regs: cvt f16 + xsq, LDS b128 writes ----
    {
      float xsq = 0.f;
#pragma unroll
      for (int g = 0; g < 8; ++g) {
        half8_t hv;
#pragma unroll
        for (int i = 0; i < 8; ++i) {
          const float v = xv[g * 8 + i];
          hv[i] = (_Float16)v; xsq += v * v;
        }
        *(half8_t*)&XbS[((w * 8 + g) * 66 + lane) * 8] = hv;
      }
      red2[w][lane] = xsq;
    }
    __syncthreads();                   // B2: XbS + red2 visible

    // ---- issue next tile's loads NOW; consumed after next B1 ----
    if (tt + 1 < TPB) {
      const float* Xg = Xbase + (size_t)(w * 64) * NPIX + (wid + (tt + 1) * NW) * TN + lane;
#pragma unroll
      for (int i = 0; i < 64; ++i) xv[i] = Xg[(size_t)i * NPIX];
    }

    // ---- phase 1 MFMA: S^T[k 16][p 64] per wave ----
    f32x4 accs[4];
#pragma unroll
    for (int nt = 0; nt < 4; ++nt) accs[nt] = (f32x4){0.f, 0.f, 0.f, 0.f};
#pragma unroll
    for (int ks = 0; ks < 8; ++ks) {
#pragma unroll
      for (int nt = 0; nt < 4; ++nt) {
        const half8_t bf = *(const half8_t*)&XbS[((ks * 4 + quad) * 66 + nt * 16 + m) * 8];
        accs[nt] = __builtin_amdgcn_mfma_f32_16x16x32_f16(af1[ks], bf, accs[nt], 0, 0, 0);
      }
    }

    // ---- phase 2: softmax; in-wave shfl + one LDS exchange ----
    float e[4][4], mw[4];
#pragma unroll
    for (int nt = 0; nt < 4; ++nt) {
      const int p = nt * 16 + m;
      const float x2p = red2[0][p] + red2[1][p] + red2[2][p] + red2[3][p];
      float L[4];
      float mx = -3.0e38f;
#pragma unroll
      for (int r = 0; r < 4; ++r) {
        L[r] = sc[r] * x2p - 2.f * sc[r] * accs[nt][r] + sq[r];
        mx = fmaxf(mx, L[r]);
      }
      mx = fmaxf(mx, __shfl_xor(mx, 16));
      mx = fmaxf(mx, __shfl_xor(mx, 32));
      float s = 0.f;
#pragma unroll
      for (int r = 0; r < 4; ++r) { e[nt][r] = __expf(L[r] - mx); s += e[nt][r]; }
      s += __shfl_xor(s, 16);
      s += __shfl_xor(s, 32);
      mw[nt] = mx;
      if (lane < 16) { redM[w][p] = mx; redS[w][p] = s; }
    }
    __syncthreads();                   // B3: cross-wave max/sum exchange
#pragma unroll
    for (int nt = 0; nt < 4; ++nt) {
      const int p = nt * 16 + m;
      const float M = fmaxf(fmaxf(redM[0][p], redM[1][p]),
                            fmaxf(redM[2][p], redM[3][p]));
      const float T = redS[0][p] * __expf(redM[0][p] - M)
                    + redS[1][p] * __expf(redM[1][p] - M)
                    + redS[2][p] * __expf(redM[2][p] - M)
                    + redS[3][p] * __expf(redM[3][p] - M);
      const float norm = __expf(mw[nt] - M) / T;
#pragma unroll
      for (int r = 0; r < 4; ++r)
        Al[kbase + quad * 4 + r][p] = (_Float16)(e[nt][r] * norm);
    }
    __syncthreads();                   // B4: Al visible

    // ---- phase 3 MFMA: E^T[d 64][k 64] per wave ----
#pragma unroll
    for (int ks = 0; ks < 2; ++ks) {
      half8_t ba[4];
#pragma unroll
      for (int kt = 0; kt < 4; ++kt)
        ba[kt] = *(const half8_t*)&Al[kt * 16 + m][ks * 32 + quad * 8];
#pragma unroll
      for (int dt = 0; dt < 4; ++dt) {
        const int c = w * 8 + dt * 2 + (m >> 3);
        const int dlow = m & 7;
        half8_t xa;
#pragma unroll
        for (int j = 0; j < 8; ++j)
          xa[j] = XbS[(c * 66 + ks * 32 + quad * 8 + j) * 8 + dlow];
#pragma unroll
        for (int kt = 0; kt < 4; ++kt)
          acc_e[dt][kt] = __builtin_amdgcn_mfma_f32_16x16x32_f16(xa, ba[kt], acc_e[dt][kt], 0, 0, 0);
      }
    }
    if (tid < NK) {                    // asum rows (wave 0)
      const half2_t one = {(_Float16)1.f, (_Float16)1.f};
#pragma unroll
      for (int lc = 0; lc < 8; ++lc) {
        const half8_t sv = *(const half8_t*)&Al[tid][lc * 8];
        asum_acc = fdot2(__builtin_shufflevector(sv, sv, 0, 1), one, asum_acc);
        asum_acc = fdot2(__builtin_shufflevector(sv, sv, 2, 3), one, asum_acc);
        asum_acc = fdot2(__builtin_shufflevector(sv, sv, 4, 5), one, asum_acc);
        asum_acc = fdot2(__builtin_shufflevector(sv, sv, 6, 7), one, asum_acc);
      }
    }
  }

  // ---- epilogue: transpose frags through LDS (XbS dead -> alias as Et) ----
  __syncthreads();
  _Float16* Et = XbS;                  // [64][264]
#pragma unroll
  for (int dt = 0; dt < 4; ++dt)
#pragma unroll
    for (int kt = 0; kt < 4; ++kt)
#pragma unroll
      for (int r = 0; r < 4; ++r) {
        const int k = kt * 16 + m;               // C/D: col=lane&15 -> k
        const int d = w * 64 + dt * 16 + quad * 4 + r;
        Et[k * 264 + d] = (_Float16)acc_e[dt][kt][r];
      }
  __syncthreads();
  const int ko = tid >> 2, cq = tid & 3;
  if (mode) {
    _Float16* Ebk = (_Float16*)Eout + (size_t)blockIdx.x * (NK * NDIM);
#pragma unroll
    for (int g = 0; g < 8; ++g)
      *(half8_t*)&Ebk[ko * NDIM + cq * 64 + g * 8] =
          *(const half8_t*)&Et[ko * 264 + cq * 64 + g * 8];
    if (tid < NK) Aout[blockIdx.x * NK + tid] = asum_acc;
  } else {
    float* Ebk = (float*)Eout + (size_t)b * (NK * NDIM);
#pragma unroll
    for (int g = 0; g < 64; ++g)
      atomicAdd(&Ebk[ko * NDIM + cq * 64 + g], (float)Et[ko * 264 + cq * 64 + g]);
    if (tid < NK) atomicAdd(&Aout[b * NK + tid], asum_acc);
  }
}

// ---- asum[b][k] = sum_w Apart[(b*NW+w)][k] ----
__global__ void asum_reduce_kernel(const float* __restrict__ Apart,
                                   float* __restrict__ asum) {
  const int i = blockIdx.x * 256 + threadIdx.x;
  const int bb = i >> 6, k = i & 63;
  float s = 0.f;
#pragma unroll 8
  for (int w = 0; w < NW; ++w) s += Apart[(bb * NW + w) * NK + k];
  asum[i] = s;
}

// ---- out = sum_w Epart(f16) - asum*C ; b128 half8 loads (R5 was u16) ----
__global__ void finalize_partials(const _Float16* __restrict__ EpartH,
                                  const float* __restrict__ asum,
                                  const float* __restrict__ Cw,
                                  float* __restrict__ out) {
  const int g = blockIdx.x * 256 + threadIdx.x;  // half8-group id, 0..32767
  const int i0 = g * 8;
  const int bb = i0 >> 14;
  const int o  = i0 & 16383;           // k*256+d within batch
  const int k  = o >> 8, d = i0 & 255;
  float s[8];
#pragma unroll
  for (int j = 0; j < 8; ++j) s[j] = 0.f;
  const _Float16* base = EpartH + (((size_t)bb * NW) << 14) + o;
#pragma unroll 4
  for (int w = 0; w < NW; ++w) {
    const half8_t v = *(const half8_t*)(base + ((size_t)w << 14));
#pragma unroll
    for (int j = 0; j < 8; ++j) s[j] += (float)v[j];
  }
  const float a = asum[bb * NK + k];
  const float4 c0 = *(const float4*)(Cw + k * NDIM + d);
  const float4 c1 = *(const float4*)(Cw + k * NDIM + d + 4);
  float4 r0, r1;
  r0.x = s[0] - a * c0.x; r0.y = s[1] - a * c0.y;
  r0.z = s[2] - a * c0.z; r0.w = s[3] - a * c0.w;
  r1.x = s[4] - a * c1.x; r1.y = s[5] - a * c1.y;
  r1.z = s[6] - a * c1.z; r1.w = s[7] - a * c1.w;
  *(float4*)(out + i0)     = r0;
  *(float4*)(out + i0 + 4) = r1;
}

// ---- out = E_acc - asum*C (atomic-fallback mode) ----
__global__ void finalize_atomic(const float* __restrict__ E_acc,
                                const float* __restrict__ asum,
                                const float* __restrict__ Cw,
                                float* __restrict__ out) {
  const int i = blockIdx.x * 256 + threadIdx.x;
  const int d = i & 255;
  const int k = (i >> 8) & 63;
  const int bb = i >> 14;
  out[i] = E_acc[i] - asum[bb * NK + k] * Cw[k * NDIM + d];
}

extern "C" void kernel_launch(void* const* d_in, const int* in_sizes, int n_in,
                              void* d_out, int out_size, void* d_ws, size_t ws_size,
                              hipStream_t stream) {
  const float* X     = (const float*)d_in[0];
  const float* Cw    = (const float*)d_in[1];
  const float* scale = (const float*)d_in[2];
  float* out = (float*)d_out;

  float* wsf = (float*)d_ws;
  _Float16* ChH = (_Float16*)(wsf + OFF_CH);
  float* c2     = wsf + OFF_C2;
  float* asum   = wsf + OFF_ASUM;
  float* Apart  = wsf + OFF_APART;

  c2ch_kernel<<<NK, 64, 0, stream>>>(Cw, c2, ChH);
  if (ws_size >= WS_NEED) {
    _Float16* EpartH = (_Float16*)(wsf + OFF_EPART);
    encode_main<<<GRID, 256, 0, stream>>>(X, ChH, scale, c2, EpartH, Apart, 1);
    asum_reduce_kernel<<<4, 256, 0, stream>>>(Apart, asum);
    finalize_partials<<<(NB*NK*NDIM)/(256*8), 256, 0, stream>>>(EpartH, asum, Cw, out);
  } else {
    float* E_acc = wsf + OFF_APART;   // fallback: fp32 atomic accumulator
    hipMemsetAsync(wsf + OFF_ASUM, 0,
                   (size_t)(NB*NK + GRID*NK + NB*NK*NDIM) * sizeof(float), stream);
    encode_main<<<GRID, 256, 0, stream>>>(X, ChH, scale, c2, E_acc, asum, 0);
    finalize_atomic<<<(NB*NK*NDIM)/256, 256, 0, stream>>>(E_acc, asum, Cw, out);
  }
}